// Round 8
// baseline (12483.867 us; speedup 1.0000x reference)
//
#include <hip/hip_runtime.h>

// DecoderGRU: 2-layer GRU (B=64, H=1024, T=1024, OUT=128) + output projection.
// R17 = R16 (flag line padding, WIN −14.5%) + three safe latency/byte cuts:
//  1) Poller fd-poll is staggered 2-deep (two flag loads in flight,
//     alternating check/reissue) -> detect granularity ~0.7 -> ~0.4us.
//  2) ew publish: last-arriving ew wave (sees all 3 LDS ewflags) stores the
//     global flag + ewdone directly; duplicate stores benign. Removes the
//     wv0-rendezvous hop from the critical publish path.
//  3) gx dump+stage in bf16 (was f32): halves S1->S2 gx transport
//     (-0.8MB/step on the shared bypass fabric). gx is O(1), bf16 rel err
//     0.4% -> negligible vs 0.0906 threshold.
// Model: step 9.59us = 5.5us bypass stream floor + ~4.1us serial chain
// (drain -> flag -> detect -> start). R16 proved flag-line contention was
// ~1.7us of it; this round attacks detect granularity + publish hops.
//   S0 (blk 0-63):   h0^t = GRU0(h0^{t-1})        [16 units/blk]
//   S1 (blk 64-127): Gx^t = y0^t @ W_ih1^T        [16 units/blk]
//   S2 (blk 128-191): h1^t = GRU1(Gx^t, h1^{t-1}) [16 units/blk]
//   S3 (blk 192-199): out^t = y1^t @ W_out^T + b  [16 cols/blk]

#define NBLK 200
#define SMEM_BYTES 152576
#define H 1024
#define T 1024
#define NSLOT 8
#define SLOT(k) (((k) + NSLOT) & (NSLOT - 1))
#define FSTR 32                       // ints per flag (128-B line)
#define MEMBAR asm volatile("" ::: "memory")

typedef short s16x8 __attribute__((ext_vector_type(8)));
typedef float f32x4 __attribute__((ext_vector_type(4)));
typedef unsigned u32x2 __attribute__((ext_vector_type(2)));
typedef int i32x4 __attribute__((ext_vector_type(4)));

__device__ __forceinline__ unsigned short f2bf(float f) {
  union { float f; unsigned u; } v; v.f = f;
  return (unsigned short)((v.u + 0x7FFFu + ((v.u >> 16) & 1u)) >> 16);
}
__device__ __forceinline__ float bf2f(unsigned short u) {
  union { unsigned u; float f; } v; v.u = (unsigned)u << 16; return v.f;
}
__device__ __forceinline__ float sigm(float x) { return 1.f / (1.f + __expf(-x)); }

__device__ __forceinline__ void st_u16(void* p, unsigned short v) {
  __hip_atomic_store((unsigned short*)p, v, __ATOMIC_RELAXED, __HIP_MEMORY_SCOPE_AGENT);
}
__device__ __forceinline__ void st_i32(int* p, int v) {
  __hip_atomic_store(p, v, __ATOMIC_RELAXED, __HIP_MEMORY_SCOPE_AGENT);
}
__device__ __forceinline__ int ld_i32(const int* p) {
  return __hip_atomic_load(p, __ATOMIC_RELAXED, __HIP_MEMORY_SCOPE_AGENT);
}
// Raw bypass flag load; compiler inserts the waitcnt at first use, so two
// of these can be kept in flight (staggered poll).
__device__ __forceinline__ int ldflag(const int* p) {
  int d;
  asm volatile("global_load_dword %0, %1, off sc0 sc1" : "=v"(d) : "v"(p));
  return d;
}

// ---- coalesced device-coherent loads/stores (bypass L1/L2) ---------------
#define GLD(d, p, off) \
  asm volatile("global_load_dwordx4 %0, %1, off offset:" #off " sc0 sc1" \
               : "=v"(d) : "v"(p))
#define GLDG(A, p) GLD(A[0],p,0); GLD(A[1],p,64); GLD(A[2],p,128); GLD(A[3],p,192)
#define WAITV(n) asm volatile("s_waitcnt vmcnt(" #n ")" ::: "memory")
#define TIE4(A) \
  asm volatile("" : "+v"(A[0]),"+v"(A[1]),"+v"(A[2]),"+v"(A[3]))

__device__ __forceinline__ void gst4(float v, void* p) {
  asm volatile("global_store_dword %0, %1, off sc0 sc1" :: "v"(p), "v"(v) : "memory");
}
__device__ __forceinline__ void gst8u(u32x2 v, void* p) {
  asm volatile("global_store_dwordx2 %0, %1, off sc0 sc1" :: "v"(p), "v"(v) : "memory");
}
__device__ __forceinline__ i32x4 gldi4(const void* p) {
  i32x4 d;
  asm volatile("global_load_dwordx4 %0, %1, off sc0 sc1" : "=v"(d) : "v"(p));
  return d;
}

// Wave-7 poller. fd section staggered 2-deep; fgx/fa sections as before.
__device__ __forceinline__ void poller(const int* fd, int dtgt,
                                       const int* fgx, int gtgt,
                                       const int* fa, int na, int atgt,
                                       volatile int* ready, int t, int lane) {
  {
    const int* fp = fd + lane * FSTR;
    int f0 = ldflag(fp);
    int f1 = ldflag(fp);
    for (;;) {
      unsigned long long m = __ballot(f0 >= dtgt);   // waits f0 (vmcnt 1)
      if (lane < 8 && ((m >> (8 * lane)) & 0xFFull) == 0xFFull) ready[lane] = t;
      if (m == ~0ull) break;
      f0 = ldflag(fp);
      m = __ballot(f1 >= dtgt);                      // waits f1 (vmcnt 1)
      if (lane < 8 && ((m >> (8 * lane)) & 0xFFull) == 0xFFull) ready[lane] = t;
      if (m == ~0ull) break;
      f1 = ldflag(fp);
    }
  }
  if (fgx) {
    int v = (lane == 0) ? ld_i32(fgx) : 0x7fffffff;
    for (;;) {
      int vn = (lane == 0) ? ld_i32(fgx) : 0x7fffffff;
      if (__ballot(v < gtgt) == 0ull) break;
      v = vn;
    }
    if (lane == 0) ready[8] = t;
  }
  if (fa) {
    bool act = lane < na;
    const int* fp = fa + (act ? lane : 0) * FSTR;
    int v = act ? ld_i32(fp) : atgt;
    for (;;) {
      int vn = act ? ld_i32(fp) : atgt;
      if (__ballot(v < atgt) == 0ull) break;
      v = vn;
    }
  }
}

#define MF3(Ap, g) { \
  _Pragma("unroll") \
  for (int i = 0; i < 4; ++i) { int kb = (g)*4 + i; \
    s16x8 b0 = *(const s16x8*)(bb + (kb*3+0)*512); \
    s16x8 b1 = *(const s16x8*)(bb + (kb*3+1)*512); \
    s16x8 b2 = *(const s16x8*)(bb + (kb*3+2)*512); \
    a0 = __builtin_amdgcn_mfma_f32_16x16x32_bf16(Ap[i], b0, a0, 0, 0, 0); \
    a1 = __builtin_amdgcn_mfma_f32_16x16x32_bf16(Ap[i], b1, a1, 0, 0, 0); \
    a2 = __builtin_amdgcn_mfma_f32_16x16x32_bf16(Ap[i], b2, a2, 0, 0, 0); } }

#define MF1(Ap, g) { \
  _Pragma("unroll") \
  for (int i = 0; i < 4; ++i) { int kb = (g)*4 + i; \
    s16x8 b0 = *(const s16x8*)(bb + kb*512); \
    a0 = __builtin_amdgcn_mfma_f32_16x16x32_bf16(Ap[i], b0, a0, 0, 0, 0); } }

// N=48 GEMM, group-pipelined (R9/R16 proven 2-deep structure).
__device__ __forceinline__ void gemm48(const unsigned short* arow,
                                       const unsigned short* bb,
                                       volatile int* ready, int t,
                                       float* G, int ldg, int lane, int w) {
  f32x4 a0 = {0,0,0,0}, a1 = {0,0,0,0}, a2 = {0,0,0,0};
  s16x8 A0[4], A1[4];
  while (ready[0] < t) {}
  MEMBAR;
  GLDG(A0, arow);
  while (ready[1] < t) {}
  MEMBAR;
  GLDG(A1, arow + 128);
  #pragma unroll
  for (int g2 = 1; g2 < 4; ++g2) {
    WAITV(4); TIE4(A0); MF3(A0, 2*g2 - 2);
    while (ready[2*g2] < t) {}
    MEMBAR;
    GLDG(A0, arow + g2*256);
    WAITV(4); TIE4(A1); MF3(A1, 2*g2 - 1);
    while (ready[2*g2 + 1] < t) {}
    MEMBAR;
    GLDG(A1, arow + g2*256 + 128);
  }
  WAITV(4); TIE4(A0); MF3(A0, 6);
  WAITV(0); TIE4(A1); MF3(A1, 7);
  int col = lane & 15, r0 = (lane >> 4) * 4;
  #pragma unroll
  for (int r = 0; r < 4; ++r) {
    int brow = w*16 + r0 + r;
    G[brow*ldg +      col] = a0[r];
    G[brow*ldg + 16 + col] = a1[r];
    G[brow*ldg + 32 + col] = a2[r];
  }
}

extern "C" __global__ void __launch_bounds__(512, 1)
gru_pipeline(const float* __restrict__ z,
             const float* __restrict__ Whh0,
             const float* __restrict__ bih0, const float* __restrict__ bhh0,
             const float* __restrict__ Wih1, const float* __restrict__ Whh1,
             const float* __restrict__ bih1, const float* __restrict__ bhh1,
             const float* __restrict__ Wout, const float* __restrict__ bout,
             float* __restrict__ out, char* __restrict__ ws)
{
  extern __shared__ char smem[];
  const int tid  = threadIdx.x;
  const int lane = tid & 63;
  const int w    = tid >> 6;
  const int bid  = blockIdx.x;

  int*            flags = (int*)ws;                         // [4][64] x FSTR ints
  unsigned short* h0    = (unsigned short*)(ws + 32768);    // 8 x 64x1024 bf16
  unsigned short* h1    = (unsigned short*)(ws + 1081344);  // 8 x 64x1024 bf16
  unsigned short* gxw16 = (unsigned short*)(ws + 2129920);  // 3 x 64x(64x48) bf16

  int role, p;
  if (bid < 64)       { role = 0; p = bid; }
  else if (bid < 128) { role = 1; p = bid - 64; }
  else if (bid < 192) { role = 2; p = bid - 128; }
  else                { role = 3; p = bid - 192; }
  const int base = p * 16;

  unsigned short* frag = (unsigned short*)smem;
  float* G   = (float*)(smem + 98304);    // 2 x 64x49 f32 (double buffer)
  float* hm  = (float*)(smem + 123392);   // fp32 master state
  float* bi  = (float*)(smem + 127488);
  float* bh  = (float*)(smem + 127680);
  volatile int* ready  = (volatile int*)(smem + 127872);  // [9]
  volatile int* gdone  = (volatile int*)(smem + 127936);  // [4]
  volatile int* ewflag = (volatile int*)(smem + 127952);  // [3]
  volatile int* gxst   = (volatile int*)(smem + 127968);  // [3]
  volatile int* ewdone = (volatile int*)(smem + 127984);  // [1]
  unsigned short* gxl16 = (unsigned short*)(smem + 128000); // S2: 2 x 3072 bf16
  float* bo  = (float*)(smem + 32768);    // S3 only (past its 32KB frags)

  int* fS0 = flags;              int* fS1 = flags + 64*FSTR;
  int* fS2 = flags + 128*FSTR;   int* fS3 = flags + 192*FSTR;

  // ---------------- init: weights -> LDS bf16 B-fragments, prefill ----------
  if (tid < 9) ready[tid] = -1;
  if (tid == 0) {
    gdone[0] = gdone[1] = gdone[2] = gdone[3] = -1;
    ewflag[0] = ewflag[1] = ewflag[2] = -1;
    gxst[0] = gxst[1] = gxst[2] = -1;
    *ewdone = -1;
  }
  if (role < 3) {
    const float* W = (role == 0) ? Whh0 : (role == 1) ? Wih1 : Whh1;
    for (int q = tid; q < 6144; q += 512) {
      int c = q % 48; int r2 = q / 48; int grp = r2 & 3; int kb = r2 >> 2;
      int g = c >> 4, u = c & 15;
      unsigned short* dst = frag + (kb*3 + g)*512 + (grp*16 + u)*8;
      const float* s = W + (size_t)(g*H + base + u)*H + kb*32 + grp*8;
      #pragma unroll
      for (int j = 0; j < 8; ++j) dst[j] = f2bf(s[j]);
    }
  }
  if (role == 0 || role == 2) {
    const float* bip = (role == 0) ? bih0 : bih1;
    const float* bhp = (role == 0) ? bhh0 : bhh1;
    if (tid < 48) {
      int g = tid >> 4, u = tid & 15;
      bi[tid] = bip[g*H + base + u];
      bh[tid] = bhp[g*H + base + u];
    }
    unsigned short* hb = (role == 0) ? h0 : h1;
    for (int q = tid; q < 1024; q += 512) {
      int b = q >> 4, u = q & 15;
      float v = z[b*H + base + u];
      hm[q] = v;
      st_u16(&hb[(NSLOT-1)*65536 + b*H + base + u], f2bf(v));  // h^{-1} slot 7
    }
  } else if (role == 3) {
    for (int q = tid; q < 2048; q += 512) {
      int c = q & 15, grp = (q >> 4) & 3, kb = q >> 6;
      unsigned short* dst = frag + kb*512 + (grp*16 + c)*8;
      const float* s = Wout + (size_t)(base + c)*H + kb*32 + grp*8;
      #pragma unroll
      for (int j = 0; j < 8; ++j) dst[j] = f2bf(s[j]);
    }
    if (tid < 16) bo[tid] = bout[base + tid];
  }
  WAITV(0);
  __syncthreads();
  if (tid == 0) st_i32(&flags[(role*64 + p)*FSTR], 1);   // data-step -1 done

  // ---------------- barrier-free steady state (roles 0-2) ------------------
  if (role < 3) {
    unsigned short* hsrc = (role == 2) ? h1 : h0;   // GEMM A source
    if (w < 4) {
      // ---- GEMM waves: free-running, double-buffered G ----
      const int ldg = (role == 1) ? 48 : 49;
      const int dt  = (role == 1) ? 0 : 1;          // A slot: t-dt
      for (int t = 0; t < 1024; ++t) {
        while (*ewdone < t - 2) {}
        MEMBAR;
        const unsigned short* arow = hsrc + SLOT(t - dt)*65536
                                     + (w*16 + (lane&15))*H + ((lane>>4)*8);
        gemm48(arow, frag + lane*8, ready, t, G + (t&1)*3136, ldg, lane, w);
        MEMBAR;
        gdone[w] = t;
      }
    } else if (w == 7) {
      // ---- poller wave (R16 targets; staggered fd poll) ----
      for (int t = 0; t < 1024; ++t) {
        if (role == 0)      poller(fS0, t+1, nullptr, 0, fS1, 64, t-1, ready, t, lane);
        else if (role == 1) poller(fS0, t+2, nullptr, 0, fS2, 64, t-1, ready, t, lane);
        else                poller(fS2, t+1, &fS1[p*FSTR], t+2, fS3, 8, t-1, ready, t, lane);
      }
    } else {
      // ---- ew waves 4-6 ----
      const int wv = w - 4;
      const int ewt = wv*64 + lane;                 // 0..191
      int* fme = flags + (role*64 + p)*FSTR;
      for (int t = 0; t < 1024; ++t) {
        if (role == 2) {
          // stage gx^t (bf16) -> gxl16[t&1] (coalesced, off the GEMM waves)
          while (ready[8] < t) {}
          MEMBAR;
          const unsigned short* gxp = gxw16 + (size_t)(t % 3)*196608 + p*3072
                                      + wv*1024 + lane*16;
          i32x4 ga = gldi4(gxp), gb = gldi4(gxp + 8);
          WAITV(0);
          asm volatile("" : "+v"(ga), "+v"(gb));
          unsigned short* dstl = gxl16 + (t&1)*3072 + wv*1024 + lane*16;
          *(i32x4*)(dstl)     = ga;
          *(i32x4*)(dstl + 8) = gb;
          MEMBAR;
          gxst[wv] = t;
          while (gxst[0] < t || gxst[1] < t || gxst[2] < t) {}
          MEMBAR;
        }
        while (gdone[0] < t || gdone[1] < t || gdone[2] < t || gdone[3] < t) {}
        MEMBAR;
        float* Gt = G + (t&1)*3136;
        if (role == 1) {
          // dump Gx to global as bf16 (halves transport)
          unsigned short* dst = gxw16 + (size_t)(t % 3)*196608 + p*3072;
          for (int c2 = ewt; c2 < 768; c2 += 192) {
            f32x4 v = *(f32x4*)(Gt + c2*4);
            u32x2 d2;
            d2.x = (unsigned)f2bf(v[0]) | ((unsigned)f2bf(v[1]) << 16);
            d2.y = (unsigned)f2bf(v[2]) | ((unsigned)f2bf(v[3]) << 16);
            gst8u(d2, dst + c2*4);
          }
        } else {
          unsigned short* gx2 = gxl16 + (t&1)*3072;
          unsigned short* hdst = hsrc + SLOT(t)*65536;
          for (int q = ewt; q < 256; q += 192) {
            int b = q >> 2, u0 = (q & 3) * 4;
            unsigned pk2[2];
            #pragma unroll
            for (int jj = 0; jj < 2; ++jj) {
              unsigned short pk[2];
              #pragma unroll
              for (int j = 0; j < 2; ++j) {
                int u = u0 + jj*2 + j;
                float xr, xz, xn;
                if (role == 0) {                 // gx = b_ih_0 (x == 0)
                  xr = bi[u]; xz = bi[16 + u]; xn = bi[32 + u];
                } else {
                  xr = bf2f(gx2[b*48 + u])      + bi[u];
                  xz = bf2f(gx2[b*48 + 16 + u]) + bi[16 + u];
                  xn = bf2f(gx2[b*48 + 32 + u]) + bi[32 + u];
                }
                float hr = Gt[b*49 + u]      + bh[u];
                float hz = Gt[b*49 + 16 + u] + bh[16 + u];
                float hn = Gt[b*49 + 32 + u] + bh[32 + u];
                float r  = sigm(xr + hr);
                float zg = sigm(xz + hz);
                float n  = tanhf(xn + r * hn);
                int idx = b*16 + u;
                float hp = hm[idx];
                float hv = (1.f - zg) * n + zg * hp;
                hm[idx] = hv;
                pk[j] = f2bf(hv);
              }
              pk2[jj] = (unsigned)pk[0] | ((unsigned)pk[1] << 16);
            }
            u32x2 v2; v2.x = pk2[0]; v2.y = pk2[1];
            gst8u(v2, &hdst[b*H + base + u0]);
          }
        }
        WAITV(0);
        MEMBAR;
        ewflag[wv] = t;
        MEMBAR;
        // last-arriving ew wave publishes (duplicates benign)
        if (ewflag[0] >= t && ewflag[1] >= t && ewflag[2] >= t) {
          if (lane == 0) st_i32(fme, t + 2);
          MEMBAR;
          *ewdone = t;
        }
      }
    }
  } else {
    // ---- S3: per-step block barrier kept ----
    for (int t = 0; t < 1024; ++t) {
      if (w == 7) {
        poller(fS2, t+2, nullptr, 0, nullptr, 0, 0, ready, t, lane);
      } else if (w < 4) {
        const unsigned short* arow = h1 + (t & (NSLOT-1))*65536
                                     + (w*16 + (lane&15))*H + ((lane>>4)*8);
        const unsigned short* bb = frag + lane*8;
        f32x4 a0 = {0,0,0,0};
        s16x8 A0[4], A1[4];
        while (ready[0] < t) {}
        MEMBAR;
        GLDG(A0, arow);
        while (ready[1] < t) {}
        MEMBAR;
        GLDG(A1, arow + 128);
        #pragma unroll
        for (int g2i = 1; g2i < 4; ++g2i) {
          WAITV(4); TIE4(A0); MF1(A0, 2*g2i - 2);
          while (ready[2*g2i] < t) {}
          MEMBAR;
          GLDG(A0, arow + g2i*256);
          WAITV(4); TIE4(A1); MF1(A1, 2*g2i - 1);
          while (ready[2*g2i + 1] < t) {}
          MEMBAR;
          GLDG(A1, arow + g2i*256 + 128);
        }
        WAITV(4); TIE4(A0); MF1(A0, 6);
        WAITV(0); TIE4(A1); MF1(A1, 7);
        int col = lane & 15, r0 = (lane >> 4) * 4;
        #pragma unroll
        for (int r = 0; r < 4; ++r) {
          int brow = w*16 + r0 + r;
          gst4(a0[r] + bo[col], out + (size_t)(brow*T + t)*128 + base + col);
        }
      }
      WAITV(0);
      __syncthreads();
      if (tid == 0) st_i32(&fS3[p*FSTR], t + 2);
    }
  }
}

extern "C" void kernel_launch(void* const* d_in, const int* in_sizes, int n_in,
                              void* d_out, int out_size, void* d_ws, size_t ws_size,
                              hipStream_t stream) {
  const float* z    = (const float*)d_in[0];
  // d_in[1] = seq_len (==1024, hard-coded); d_in[2] = W_ih_0 (unused: x0==0)
  const float* Whh0 = (const float*)d_in[3];
  const float* bih0 = (const float*)d_in[4];
  const float* bhh0 = (const float*)d_in[5];
  const float* Wih1 = (const float*)d_in[6];
  const float* Whh1 = (const float*)d_in[7];
  const float* bih1 = (const float*)d_in[8];
  const float* bhh1 = (const float*)d_in[9];
  const float* Wout = (const float*)d_in[10];
  const float* bout = (const float*)d_in[11];
  float* out = (float*)d_out;
  char* ws = (char*)d_ws;

  hipFuncSetAttribute((const void*)gru_pipeline,
                      hipFuncAttributeMaxDynamicSharedMemorySize, SMEM_BYTES);
  hipMemsetAsync(d_ws, 0, 32768, stream);   // line-strided flags

  void* args[] = { (void*)&z, (void*)&Whh0, (void*)&bih0, (void*)&bhh0,
                   (void*)&Wih1, (void*)&Whh1, (void*)&bih1, (void*)&bhh1,
                   (void*)&Wout, (void*)&bout, (void*)&out, (void*)&ws };
  hipLaunchCooperativeKernel((void*)gru_pipeline, dim3(NBLK), dim3(512),
                             args, SMEM_BYTES, stream);
}

// Round 9
// 8085.462 us; speedup vs baseline: 1.5440x; 1.5440x over previous
//
#include <hip/hip_runtime.h>

// DecoderGRU: 2-layer GRU (B=64, H=1024, T=1024, OUT=128) + output projection.
// R18 = R16 (proven 9.82ms: line-padded flags, simple poll, f32 gx) + ONE
// change: EW FUSED INTO GEMM EPILOGUE. The gemm48 epilogue thread holds all
// 3 gates of (batch b, unit u) in a0/a1/a2[r] -> do sigmoid/tanh/h-update
// inline, store h (2B bypass) directly. Deletes from the per-step critical
// chain: G LDS write, gdone rendezvous, ew wave wakeup, Gt re-reads, ew
// drain. S2's gx tile is staged to LDS by the POLLER wave after its fd
// section (gx needed only at epilogue ~5.5us later; fS1 gate proves ready;
// staging of t+1 cannot overwrite gxl being read since it requires our own
// fS2=t+2, published after the epilogue). S1/S3 store outputs directly in
// epilogue. Blocks are 5 waves (320 thr): 4 gemm + 1 poller. Flag publish:
// per-wave drain -> gdone[w] (LDS) -> last-arriving wave stores flag t+2.
// All R16 gating targets/slot proofs unchanged. R17's three changes reverted.
//   S0 (blk 0-63):   h0^t = GRU0(h0^{t-1})        [16 units/blk]
//   S1 (blk 64-127): Gx^t = y0^t @ W_ih1^T        [16 units/blk]
//   S2 (blk 128-191): h1^t = GRU1(Gx^t, h1^{t-1}) [16 units/blk]
//   S3 (blk 192-199): out^t = y1^t @ W_out^T + b  [16 cols/blk]

#define NBLK 200
#define NTHR 320
#define SMEM_BYTES 152576
#define H 1024
#define T 1024
#define NSLOT 8
#define SLOT(k) (((k) + NSLOT) & (NSLOT - 1))
#define FSTR 32                       // ints per flag (128-B line)
#define MEMBAR asm volatile("" ::: "memory")

typedef short s16x8 __attribute__((ext_vector_type(8)));
typedef float f32x4 __attribute__((ext_vector_type(4)));

__device__ __forceinline__ unsigned short f2bf(float f) {
  union { float f; unsigned u; } v; v.f = f;
  return (unsigned short)((v.u + 0x7FFFu + ((v.u >> 16) & 1u)) >> 16);
}
__device__ __forceinline__ float sigm(float x) { return 1.f / (1.f + __expf(-x)); }

__device__ __forceinline__ void st_u16(void* p, unsigned short v) {
  __hip_atomic_store((unsigned short*)p, v, __ATOMIC_RELAXED, __HIP_MEMORY_SCOPE_AGENT);
}
__device__ __forceinline__ void st_i32(int* p, int v) {
  __hip_atomic_store(p, v, __ATOMIC_RELAXED, __HIP_MEMORY_SCOPE_AGENT);
}
__device__ __forceinline__ int ld_i32(const int* p) {
  return __hip_atomic_load(p, __ATOMIC_RELAXED, __HIP_MEMORY_SCOPE_AGENT);
}

// ---- coalesced device-coherent loads/stores (bypass L1/L2) ---------------
#define GLD(d, p, off) \
  asm volatile("global_load_dwordx4 %0, %1, off offset:" #off " sc0 sc1" \
               : "=v"(d) : "v"(p))
#define GLDG(A, p) GLD(A[0],p,0); GLD(A[1],p,64); GLD(A[2],p,128); GLD(A[3],p,192)
#define WAITV(n) asm volatile("s_waitcnt vmcnt(" #n ")" ::: "memory")
#define TIE4(A) \
  asm volatile("" : "+v"(A[0]),"+v"(A[1]),"+v"(A[2]),"+v"(A[3]))

__device__ __forceinline__ void gst4(float v, void* p) {
  asm volatile("global_store_dword %0, %1, off sc0 sc1" :: "v"(p), "v"(v) : "memory");
}
__device__ __forceinline__ void gsts(unsigned short v, void* p) {
  asm volatile("global_store_short %0, %1, off sc0 sc1" :: "v"(p), "v"((unsigned)v) : "memory");
}
__device__ __forceinline__ f32x4 gldf(const float* p) {
  f32x4 d;
  asm volatile("global_load_dwordx4 %0, %1, off sc0 sc1" : "=v"(d) : "v"(p));
  return d;
}

// fd poll (R16 simple loop) with progressive ready release.
__device__ __forceinline__ void pollfd(const int* fd, int dtgt,
                                       volatile int* ready, int t, int lane) {
  const int* fp = fd + lane * FSTR;
  int v = ld_i32(fp);
  for (;;) {
    int vn = ld_i32(fp);
    unsigned long long m = __ballot(v >= dtgt);
    if (lane < 8 && ((m >> (8 * lane)) & 0xFFull) == 0xFFull) ready[lane] = t;
    if (m == ~0ull) break;
    v = vn;
  }
}
// fa anti-runahead poll.
__device__ __forceinline__ void pollfa(const int* fa, int na, int atgt, int lane) {
  bool act = lane < na;
  const int* fp = fa + (act ? lane : 0) * FSTR;
  int v = act ? ld_i32(fp) : atgt;
  for (;;) {
    int vn = act ? ld_i32(fp) : atgt;
    if (__ballot(v < atgt) == 0ull) break;
    v = vn;
  }
}

#define MF3(Ap, g) { \
  _Pragma("unroll") \
  for (int i = 0; i < 4; ++i) { int kb = (g)*4 + i; \
    s16x8 b0 = *(const s16x8*)(bb + (kb*3+0)*512); \
    s16x8 b1 = *(const s16x8*)(bb + (kb*3+1)*512); \
    s16x8 b2 = *(const s16x8*)(bb + (kb*3+2)*512); \
    a0 = __builtin_amdgcn_mfma_f32_16x16x32_bf16(Ap[i], b0, a0, 0, 0, 0); \
    a1 = __builtin_amdgcn_mfma_f32_16x16x32_bf16(Ap[i], b1, a1, 0, 0, 0); \
    a2 = __builtin_amdgcn_mfma_f32_16x16x32_bf16(Ap[i], b2, a2, 0, 0, 0); } }

#define MF1(Ap, g) { \
  _Pragma("unroll") \
  for (int i = 0; i < 4; ++i) { int kb = (g)*4 + i; \
    s16x8 b0 = *(const s16x8*)(bb + kb*512); \
    a0 = __builtin_amdgcn_mfma_f32_16x16x32_bf16(Ap[i], b0, a0, 0, 0, 0); } }

// N=48 GEMM A/MFMA pipeline (R9/R16 proven 2-deep). Results left in a0/a1/a2.
#define GEMM48_BODY(arow) \
  f32x4 a0 = {0,0,0,0}, a1 = {0,0,0,0}, a2 = {0,0,0,0}; \
  { s16x8 A0[4], A1[4]; \
    while (ready[0] < t) {} \
    MEMBAR; \
    GLDG(A0, arow); \
    while (ready[1] < t) {} \
    MEMBAR; \
    GLDG(A1, arow + 128); \
    _Pragma("unroll") \
    for (int g2 = 1; g2 < 4; ++g2) { \
      WAITV(4); TIE4(A0); MF3(A0, 2*g2 - 2); \
      while (ready[2*g2] < t) {} \
      MEMBAR; \
      GLDG(A0, arow + g2*256); \
      WAITV(4); TIE4(A1); MF3(A1, 2*g2 - 1); \
      while (ready[2*g2 + 1] < t) {} \
      MEMBAR; \
      GLDG(A1, arow + g2*256 + 128); \
    } \
    WAITV(4); TIE4(A0); MF3(A0, 6); \
    WAITV(0); TIE4(A1); MF3(A1, 7); }

extern "C" __global__ void __launch_bounds__(NTHR, 1)
gru_pipeline(const float* __restrict__ z,
             const float* __restrict__ Whh0,
             const float* __restrict__ bih0, const float* __restrict__ bhh0,
             const float* __restrict__ Wih1, const float* __restrict__ Whh1,
             const float* __restrict__ bih1, const float* __restrict__ bhh1,
             const float* __restrict__ Wout, const float* __restrict__ bout,
             float* __restrict__ out, char* __restrict__ ws)
{
  extern __shared__ char smem[];
  const int tid  = threadIdx.x;
  const int lane = tid & 63;
  const int w    = tid >> 6;
  const int bid  = blockIdx.x;

  int*            flags = (int*)ws;                         // [4][64] x FSTR ints
  unsigned short* h0    = (unsigned short*)(ws + 32768);    // 8 x 64x1024 bf16
  unsigned short* h1    = (unsigned short*)(ws + 1081344);  // 8 x 64x1024 bf16
  float*          gxw   = (float*)(ws + 2129920);           // 3 x 64x(64x48) f32

  int role, p;
  if (bid < 64)       { role = 0; p = bid; }
  else if (bid < 128) { role = 1; p = bid - 64; }
  else if (bid < 192) { role = 2; p = bid - 128; }
  else                { role = 3; p = bid - 192; }
  const int base = p * 16;

  unsigned short* frag = (unsigned short*)smem;
  float* hm  = (float*)(smem + 123392);   // fp32 master state (roles 0,2)
  float* bi  = (float*)(smem + 127488);
  float* bh  = (float*)(smem + 127680);
  volatile int* ready  = (volatile int*)(smem + 127872);  // [9]
  volatile int* gdone  = (volatile int*)(smem + 127936);  // [4]
  float* gxl = (float*)(smem + 128000);   // S2: 2 x 64x48 f32 (poller-staged)
  float* bo  = (float*)(smem + 32768);    // S3 only (past its 32KB frags)

  int* fS0 = flags;              int* fS1 = flags + 64*FSTR;
  int* fS2 = flags + 128*FSTR;   int* fS3 = flags + 192*FSTR;

  // ---------------- init: weights -> LDS bf16 B-fragments, prefill ----------
  if (tid < 9) ready[tid] = -1;
  if (tid == 0) { gdone[0] = gdone[1] = gdone[2] = gdone[3] = -1; }
  if (role < 3) {
    const float* W = (role == 0) ? Whh0 : (role == 1) ? Wih1 : Whh1;
    for (int q = tid; q < 6144; q += NTHR) {
      int c = q % 48; int r2 = q / 48; int grp = r2 & 3; int kb = r2 >> 2;
      int g = c >> 4, u = c & 15;
      unsigned short* dst = frag + (kb*3 + g)*512 + (grp*16 + u)*8;
      const float* s = W + (size_t)(g*H + base + u)*H + kb*32 + grp*8;
      #pragma unroll
      for (int j = 0; j < 8; ++j) dst[j] = f2bf(s[j]);
    }
  }
  if (role == 0 || role == 2) {
    const float* bip = (role == 0) ? bih0 : bih1;
    const float* bhp = (role == 0) ? bhh0 : bhh1;
    if (tid < 48) {
      int g = tid >> 4, u = tid & 15;
      bi[tid] = bip[g*H + base + u];
      bh[tid] = bhp[g*H + base + u];
    }
    unsigned short* hb = (role == 0) ? h0 : h1;
    for (int q = tid; q < 1024; q += NTHR) {
      int b = q >> 4, u = q & 15;
      float v = z[b*H + base + u];
      hm[q] = v;
      st_u16(&hb[(NSLOT-1)*65536 + b*H + base + u], f2bf(v));  // h^{-1} slot 7
    }
  } else if (role == 3) {
    for (int q = tid; q < 2048; q += NTHR) {
      int c = q & 15, grp = (q >> 4) & 3, kb = q >> 6;
      unsigned short* dst = frag + kb*512 + (grp*16 + c)*8;
      const float* s = Wout + (size_t)(base + c)*H + kb*32 + grp*8;
      #pragma unroll
      for (int j = 0; j < 8; ++j) dst[j] = f2bf(s[j]);
    }
    if (tid < 16) bo[tid] = bout[base + tid];
  }
  WAITV(0);
  __syncthreads();
  if (tid == 0) st_i32(&flags[(role*64 + p)*FSTR], 1);   // data-step -1 done

  // ---------------- barrier-free steady state ------------------------------
  if (role < 3) {
    unsigned short* hsrc = (role == 2) ? h1 : h0;   // GEMM A source
    if (w == 4) {
      // ---- poller wave ----
      for (int t = 0; t < 1024; ++t) {
        if (role == 0) {
          pollfd(fS0, t+1, ready, t, lane);
          pollfa(fS1, 64, t-1, lane);
        } else if (role == 1) {
          pollfd(fS0, t+2, ready, t, lane);
          pollfa(fS2, 64, t-1, lane);
        } else {
          pollfd(fS2, t+1, ready, t, lane);
          // gx^t availability (fS1[p] >= t+2), then stage gx -> gxl[t&1]
          {
            int v = (lane == 0) ? ld_i32(&fS1[p*FSTR]) : 0x7fffffff;
            while (__ballot(v < t+2) != 0ull)
              v = (lane == 0) ? ld_i32(&fS1[p*FSTR]) : 0x7fffffff;
          }
          MEMBAR;
          const float* gxp = gxw + (size_t)(t % 3)*196608 + p*3072 + lane*48;
          f32x4 g0 = gldf(gxp),      g1 = gldf(gxp + 4),  g2 = gldf(gxp + 8);
          f32x4 g3 = gldf(gxp + 12), g4 = gldf(gxp + 16), g5 = gldf(gxp + 20);
          f32x4 g6 = gldf(gxp + 24), g7 = gldf(gxp + 28), g8 = gldf(gxp + 32);
          f32x4 g9 = gldf(gxp + 36), ga = gldf(gxp + 40), gb2 = gldf(gxp + 44);
          WAITV(0);
          float* dl = gxl + (t&1)*3072 + lane*48;
          *(f32x4*)(dl)      = g0; *(f32x4*)(dl + 4)  = g1; *(f32x4*)(dl + 8)  = g2;
          *(f32x4*)(dl + 12) = g3; *(f32x4*)(dl + 16) = g4; *(f32x4*)(dl + 20) = g5;
          *(f32x4*)(dl + 24) = g6; *(f32x4*)(dl + 28) = g7; *(f32x4*)(dl + 32) = g8;
          *(f32x4*)(dl + 36) = g9; *(f32x4*)(dl + 40) = ga; *(f32x4*)(dl + 44) = gb2;
          MEMBAR;
          if (lane == 0) ready[8] = t;
          MEMBAR;
          pollfa(fS3, 8, t-1, lane);
        }
      }
    } else {
      // ---- GEMM + fused-ew waves (w = 0..3) ----
      const int dt  = (role == 1) ? 0 : 1;          // A slot: t-dt
      int* fme = flags + (role*64 + p)*FSTR;
      const int col = lane & 15, r0 = (lane >> 4) * 4;
      for (int t = 0; t < 1024; ++t) {
        const unsigned short* arow = hsrc + SLOT(t - dt)*65536
                                     + (w*16 + col)*H + ((lane>>4)*8);
        const unsigned short* bb = frag + lane*8;
        GEMM48_BODY(arow);
        // ---- fused epilogue ----
        if (role == 1) {
          // store Gx^t (raw, f32) to gxw
          float* dst = gxw + (size_t)(t % 3)*196608 + p*3072;
          #pragma unroll
          for (int r = 0; r < 4; ++r) {
            int b = w*16 + r0 + r;
            gst4(a0[r], dst + b*48 +      col);
            gst4(a1[r], dst + b*48 + 16 + col);
            gst4(a2[r], dst + b*48 + 32 + col);
          }
        } else {
          float* gx2 = gxl + (t&1)*3072;
          if (role == 2) {
            while (ready[8] < t) {}
            MEMBAR;
          }
          unsigned short* hdst = hsrc + SLOT(t)*65536;
          #pragma unroll
          for (int r = 0; r < 4; ++r) {
            int b = w*16 + r0 + r;
            float xr, xz, xn;
            if (role == 0) {                 // gx = b_ih_0 (x == 0)
              xr = bi[col]; xz = bi[16 + col]; xn = bi[32 + col];
            } else {
              xr = gx2[b*48 +      col] + bi[col];
              xz = gx2[b*48 + 16 + col] + bi[16 + col];
              xn = gx2[b*48 + 32 + col] + bi[32 + col];
            }
            float hr = a0[r] + bh[col];
            float hz = a1[r] + bh[16 + col];
            float hn = a2[r] + bh[32 + col];
            float rg = sigm(xr + hr);
            float zg = sigm(xz + hz);
            float n  = tanhf(xn + rg * hn);
            int idx = b*16 + col;
            float hp = hm[idx];
            float hv = (1.f - zg) * n + zg * hp;
            hm[idx] = hv;
            gsts(f2bf(hv), &hdst[b*H + base + col]);
          }
        }
        WAITV(0);     // drain output stores
        MEMBAR;
        gdone[w] = t;
        MEMBAR;
        // last-arriving gemm wave publishes (duplicates benign)
        if (gdone[0] >= t && gdone[1] >= t && gdone[2] >= t && gdone[3] >= t) {
          if (lane == 0) st_i32(fme, t + 2);
        }
      }
    }
  } else {
    // ---- S3: 4 gemm waves + poller, barrier-free ----
    for (int t = 0; t < 1024; ++t) {
      if (w == 4) {
        pollfd(fS2, t+2, ready, t, lane);
      } else {
        const unsigned short* arow = h1 + (t & (NSLOT-1))*65536
                                     + (w*16 + (lane&15))*H + ((lane>>4)*8);
        const unsigned short* bb = frag + lane*8;
        f32x4 a0 = {0,0,0,0};
        s16x8 A0[4], A1[4];
        while (ready[0] < t) {}
        MEMBAR;
        GLDG(A0, arow);
        while (ready[1] < t) {}
        MEMBAR;
        GLDG(A1, arow + 128);
        #pragma unroll
        for (int g2i = 1; g2i < 4; ++g2i) {
          WAITV(4); TIE4(A0); MF1(A0, 2*g2i - 2);
          while (ready[2*g2i] < t) {}
          MEMBAR;
          GLDG(A0, arow + g2i*256);
          WAITV(4); TIE4(A1); MF1(A1, 2*g2i - 1);
          while (ready[2*g2i + 1] < t) {}
          MEMBAR;
          GLDG(A1, arow + g2i*256 + 128);
        }
        WAITV(4); TIE4(A0); MF1(A0, 6);
        WAITV(0); TIE4(A1); MF1(A1, 7);
        int col = lane & 15, r0 = (lane >> 4) * 4;
        #pragma unroll
        for (int r = 0; r < 4; ++r) {
          int brow = w*16 + r0 + r;
          gst4(a0[r] + bo[col], out + (size_t)(brow*T + t)*128 + base + col);
        }
        WAITV(0);
        MEMBAR;
        gdone[w] = t;
        MEMBAR;
        if (gdone[0] >= t && gdone[1] >= t && gdone[2] >= t && gdone[3] >= t) {
          if (lane == 0) st_i32(&fS3[p*FSTR], t + 2);
        }
      }
    }
  }
}

extern "C" void kernel_launch(void* const* d_in, const int* in_sizes, int n_in,
                              void* d_out, int out_size, void* d_ws, size_t ws_size,
                              hipStream_t stream) {
  const float* z    = (const float*)d_in[0];
  // d_in[1] = seq_len (==1024, hard-coded); d_in[2] = W_ih_0 (unused: x0==0)
  const float* Whh0 = (const float*)d_in[3];
  const float* bih0 = (const float*)d_in[4];
  const float* bhh0 = (const float*)d_in[5];
  const float* Wih1 = (const float*)d_in[6];
  const float* Whh1 = (const float*)d_in[7];
  const float* bih1 = (const float*)d_in[8];
  const float* bhh1 = (const float*)d_in[9];
  const float* Wout = (const float*)d_in[10];
  const float* bout = (const float*)d_in[11];
  float* out = (float*)d_out;
  char* ws = (char*)d_ws;

  hipFuncSetAttribute((const void*)gru_pipeline,
                      hipFuncAttributeMaxDynamicSharedMemorySize, SMEM_BYTES);
  hipMemsetAsync(d_ws, 0, 32768, stream);   // line-strided flags

  void* args[] = { (void*)&z, (void*)&Whh0, (void*)&bih0, (void*)&bhh0,
                   (void*)&Wih1, (void*)&Whh1, (void*)&bih1, (void*)&bhh1,
                   (void*)&Wout, (void*)&bout, (void*)&out, (void*)&ws };
  hipLaunchCooperativeKernel((void*)gru_pipeline, dim3(NBLK), dim3(NTHR),
                             args, SMEM_BYTES, stream);
}